// Round 1
// 470.330 us; speedup vs baseline: 1.0309x; 1.0309x over previous
//
#include <hip/hip_runtime.h>
#include <cstdint>
#include <cstddef>

#define NN 50000
#define NE 200000
#define IND 768
#define HID 256
#define OUTD 64
#define NB 196  // ceil(NN/256)

typedef __bf16 bf16;
typedef __bf16 bf16x8 __attribute__((ext_vector_type(8)));
typedef float f32x4 __attribute__((ext_vector_type(4)));

// ---------------- edge prep: last-write-wins scatter index + dst histogram ----------------
__global__ __launch_bounds__(256) void k_edge_prep(const int* __restrict__ ei,
                                                   int* __restrict__ le, int* __restrict__ deg) {
  int e = blockIdx.x * 256 + threadIdx.x;
  if (e < NE) {
    atomicMax(&le[ei[e]], e);        // src: last edge index wins
    atomicAdd(&deg[ei[NE + e]], 1);  // dst degree
  }
}

// eembz: [R+1][IND], rows 0..5 = eemb, row 6 = zeros (branchless "no edge" row)
__global__ __launch_bounds__(256) void k_eembz(const float* __restrict__ eemb,
                                               float* __restrict__ ez) {
  int i = blockIdx.x * 256 + threadIdx.x;
  if (i < 7 * IND) ez[i] = (i < 6 * IND) ? eemb[i] : 0.f;
}

// ---------------- CSR build: scan + scatter ----------------
__global__ __launch_bounds__(256) void k_scan_block(const int* __restrict__ deg,
                                                    int* __restrict__ excl, int* __restrict__ bsum) {
  __shared__ int sm[256];
  int tid = threadIdx.x;
  int i = blockIdx.x * 256 + tid;
  int v = (i < NN) ? deg[i] : 0;
  sm[tid] = v;
  __syncthreads();
#pragma unroll
  for (int off = 1; off < 256; off <<= 1) {
    int t = (tid >= off) ? sm[tid - off] : 0;
    __syncthreads();
    sm[tid] += t;
    __syncthreads();
  }
  if (i < NN) excl[i] = sm[tid] - v;
  if (tid == 255) bsum[blockIdx.x] = sm[255];
}

__global__ __launch_bounds__(256) void k_scan_partials(const int* __restrict__ bsum,
                                                       int* __restrict__ bbase) {
  __shared__ int sm[256];
  int tid = threadIdx.x;
  int v = (tid < NB) ? bsum[tid] : 0;
  sm[tid] = v;
  __syncthreads();
#pragma unroll
  for (int off = 1; off < 256; off <<= 1) {
    int t = (tid >= off) ? sm[tid - off] : 0;
    __syncthreads();
    sm[tid] += t;
    __syncthreads();
  }
  bbase[tid] = sm[tid] - v;
}

__global__ __launch_bounds__(256) void k_add_base(const int* __restrict__ excl,
                                                  const int* __restrict__ bbase,
                                                  int* __restrict__ rowstart, int* __restrict__ cur) {
  int i = blockIdx.x * 256 + threadIdx.x;
  if (i < NN) {
    int rs = excl[i] + bbase[i >> 8];
    rowstart[i] = rs;
    cur[i] = rs;
  }
}

__global__ __launch_bounds__(256) void k_scatter_csr(const int* __restrict__ ei,
                                                     int* __restrict__ cur, int* __restrict__ csr) {
  int e = blockIdx.x * 256 + threadIdx.x;
  if (e < NE) {
    int d = ei[NE + e];
    int pos = atomicAdd(&cur[d], 1);
    csr[pos] = ei[e];  // store src node id
  }
}

// W [K, NC] fp32 -> Wt [NC, K] bf16
__global__ __launch_bounds__(256) void k_transpose(const float* __restrict__ W,
                                                   bf16* __restrict__ Wt, int K, int NC) {
  int k = blockIdx.x * 256 + threadIdx.x;
  int n = blockIdx.y;
  if (k < K) Wt[n * K + k] = (bf16)W[k * NC + n];
}

// ---------------- MFMA GEMM: C[M,NC] = A[M,K] * Bt[NC,K]^T ----------------
// 128x128 tile, BK=32, 4 waves 2x2, each wave 64x64 (4x4 of 16x16x32 MFMA).
// Pipelined: register prefetch distance 1 (T14 issue-early/commit-late) +
// double-buffered LDS (one barrier per K-step) + padded LDS rows (40 bf16 =
// 80B, breaks the 64B-stride 8-way bank conflict while keeping b128 align).
// FUSE: A built on the fly as bf16(x[row] + eembz[e]) where e=6 (zero row)
// for rows with no incident src edge -> branchless unconditional loads.
// Epilogue also emits attention logits alS/alD (per-row dot with aS/aD).
template <typename OutT, bool FUSE>
__global__ __launch_bounds__(256) void k_gemm_bt(const bf16* __restrict__ A,
                                                 const float* __restrict__ Ax,
                                                 const int* __restrict__ le,
                                                 const int* __restrict__ et,
                                                 const float* __restrict__ eembz,
                                                 const bf16* __restrict__ Bt,
                                                 OutT* __restrict__ C,
                                                 int M, int K, int NC,
                                                 const float* __restrict__ aS,
                                                 const float* __restrict__ aD,
                                                 float* __restrict__ alS,
                                                 float* __restrict__ alD,
                                                 int alStride) {
  constexpr int PAD = 40;  // bf16 per LDS row: 32 data + 8 pad (80B, 16B-aligned)
  __shared__ bf16 As[2][128 * PAD];
  __shared__ bf16 Bs[2][128 * PAD];
  const int tid = threadIdx.x;
  const int lane = tid & 63;
  const int wave = tid >> 6;
  const int wr = wave >> 1, wc = wave & 1;
  const int ln15 = lane & 15, q = lane >> 4;
  const int n0 = blockIdx.x * 128;  // n fastest-varying: adjacent blocks share A-tile
  const int m0 = blockIdx.y * 128;
  const int r0 = tid >> 2;
  const int ce = (tid & 3) << 3;

  const int rA1 = min(m0 + r0, M - 1);
  const int rA2 = min(m0 + 64 + r0, M - 1);
  const int rB1 = min(n0 + r0, NC - 1);
  const int rB2 = min(n0 + 64 + r0, NC - 1);

  const float* pA1 = nullptr; const float* pA2 = nullptr;
  const float* pE1 = nullptr; const float* pE2 = nullptr;
  const bf16* pAb1 = nullptr; const bf16* pAb2 = nullptr;
  if constexpr (FUSE) {
    int l1 = le[rA1]; int e1 = (l1 >= 0) ? et[l1] : 6;
    int l2 = le[rA2]; int e2 = (l2 >= 0) ? et[l2] : 6;
    pA1 = Ax + (size_t)rA1 * K + ce;
    pA2 = Ax + (size_t)rA2 * K + ce;
    pE1 = eembz + (size_t)e1 * K + ce;
    pE2 = eembz + (size_t)e2 * K + ce;
  } else {
    pAb1 = A + (size_t)rA1 * K + ce;
    pAb2 = A + (size_t)rA2 * K + ce;
  }
  const bf16* pB1 = Bt + (size_t)rB1 * K + ce;
  const bf16* pB2 = Bt + (size_t)rB2 * K + ce;

  // staging registers (live across issue -> commit)
  float4 a0, a1, b0, b1, t0, t1, t2, t3;
  int4 va_i, vb_i, wb1, wb2;

  auto issue = [&](int kt) {  // issue global loads for K-tile kt (no use yet)
    if constexpr (FUSE) {
      a0 = *(const float4*)(pA1 + kt);
      a1 = *(const float4*)(pA1 + kt + 4);
      b0 = *(const float4*)(pA2 + kt);
      b1 = *(const float4*)(pA2 + kt + 4);
      t0 = *(const float4*)(pE1 + kt);
      t1 = *(const float4*)(pE1 + kt + 4);
      t2 = *(const float4*)(pE2 + kt);
      t3 = *(const float4*)(pE2 + kt + 4);
    } else {
      va_i = *(const int4*)(pAb1 + kt);
      vb_i = *(const int4*)(pAb2 + kt);
    }
    wb1 = *(const int4*)(pB1 + kt);
    wb2 = *(const int4*)(pB2 + kt);
  };

  auto commit = [&](int buf) {  // fuse+convert+write LDS (forces vmcnt wait here)
    if constexpr (FUSE) {
      bf16x8 va, vb;
      va[0] = (bf16)(a0.x + t0.x); va[1] = (bf16)(a0.y + t0.y);
      va[2] = (bf16)(a0.z + t0.z); va[3] = (bf16)(a0.w + t0.w);
      va[4] = (bf16)(a1.x + t1.x); va[5] = (bf16)(a1.y + t1.y);
      va[6] = (bf16)(a1.z + t1.z); va[7] = (bf16)(a1.w + t1.w);
      vb[0] = (bf16)(b0.x + t2.x); vb[1] = (bf16)(b0.y + t2.y);
      vb[2] = (bf16)(b0.z + t2.z); vb[3] = (bf16)(b0.w + t2.w);
      vb[4] = (bf16)(b1.x + t3.x); vb[5] = (bf16)(b1.y + t3.y);
      vb[6] = (bf16)(b1.z + t3.z); vb[7] = (bf16)(b1.w + t3.w);
      *(bf16x8*)(&As[buf][r0 * PAD + ce]) = va;
      *(bf16x8*)(&As[buf][(64 + r0) * PAD + ce]) = vb;
    } else {
      *(int4*)(&As[buf][r0 * PAD + ce]) = va_i;
      *(int4*)(&As[buf][(64 + r0) * PAD + ce]) = vb_i;
    }
    *(int4*)(&Bs[buf][r0 * PAD + ce]) = wb1;
    *(int4*)(&Bs[buf][(64 + r0) * PAD + ce]) = wb2;
  };

  f32x4 acc[4][4] = {};

  auto compute = [&](int buf) {  // ds_read frags + 16 MFMA
    bf16x8 af[4], bfr[4];
#pragma unroll
    for (int i = 0; i < 4; i++)
      af[i] = *(const bf16x8*)(&As[buf][(wr * 64 + i * 16 + ln15) * PAD + q * 8]);
#pragma unroll
    for (int i = 0; i < 4; i++)
      bfr[i] = *(const bf16x8*)(&Bs[buf][(wc * 64 + i * 16 + ln15) * PAD + q * 8]);
#pragma unroll
    for (int mi = 0; mi < 4; mi++)
#pragma unroll
      for (int ni = 0; ni < 4; ni++)
        acc[mi][ni] = __builtin_amdgcn_mfma_f32_16x16x32_bf16(af[mi], bfr[ni], acc[mi][ni], 0, 0, 0);
  };

  const int NT = K >> 5;

  // prologue: stage tile 0
  issue(0);
  commit(0);
  __syncthreads();

  int cur = 0;
  for (int t = 0; t < NT - 1; ++t) {
    issue((t + 1) << 5);   // prefetch next tile into regs (overlaps compute)
    compute(cur);          // ds_read buf[cur] + MFMA
    commit(cur ^ 1);       // vmcnt wait lands here, after the MFMAs
    __syncthreads();       // single barrier per K-step (dbuf: WAR safe, RAW published)
    cur ^= 1;
  }
  compute(cur);  // last tile, no prefetch/commit

  // epilogue 1: C store. C/D layout col=lane&15, row=(lane>>4)*4+reg
#pragma unroll
  for (int mi = 0; mi < 4; mi++)
#pragma unroll
    for (int ni = 0; ni < 4; ni++)
#pragma unroll
      for (int r = 0; r < 4; r++) {
        int row = m0 + wr * 64 + mi * 16 + q * 4 + r;
        int col = n0 + wc * 64 + ni * 16 + ln15;
        if (row < M && col < NC) C[(size_t)row * NC + col] = (OutT)acc[mi][ni][r];
      }

  // epilogue 2: attention logits. Each wave's 64-col slice == one head slice
  // (hd constant per wave); each (row, hd) is produced by exactly one wave
  // grid-wide -> plain stores, no atomics.
  if (n0 + wc * 64 < NC) {
    const int hd = (n0 + wc * 64) >> 6;
#pragma unroll
    for (int mi = 0; mi < 4; mi++)
#pragma unroll
      for (int r = 0; r < 4; r++) {
        float ps = 0.f, pd = 0.f;
#pragma unroll
        for (int ni = 0; ni < 4; ni++) {
          int col = n0 + wc * 64 + ni * 16 + ln15;
          float w_s = (col < NC) ? aS[col] : 0.f;
          float w_d = (col < NC) ? aD[col] : 0.f;
          ps += acc[mi][ni][r] * w_s;
          pd += acc[mi][ni][r] * w_d;
        }
#pragma unroll
        for (int off = 1; off < 16; off <<= 1) {
          ps += __shfl_xor(ps, off);
          pd += __shfl_xor(pd, off);
        }
        int row = m0 + wr * 64 + mi * 16 + q * 4 + r;
        if (ln15 == 0 && row < M) {
          alS[row * alStride + hd] = ps;
          alD[row * alStride + hd] = pd;
        }
      }
  }
}

// ---------------- fused gather-aggregate + LN + ELU, layer 1 ----------------
__global__ __launch_bounds__(256) void k_agg_ln1(const int* __restrict__ rowstart,
                                                 const int* __restrict__ deg,
                                                 const int* __restrict__ csr,
                                                 const bf16* __restrict__ h1,
                                                 const float* __restrict__ alS,
                                                 const float* __restrict__ alD,
                                                 const float* __restrict__ b1,
                                                 const float* __restrict__ g1,
                                                 const float* __restrict__ be1,
                                                 bf16* __restrict__ hln) {
  __shared__ float red[8];
  int n = blockIdx.x, f = threadIdx.x, hd = f >> 6;
  int start = rowstart[n], cnt = deg[n];
  float ald = alD[n * 4 + hd];
  float accv = 0.f, accw = 0.f;
  for (int j = 0; j < cnt; j++) {
    int s = csr[start + j];
    float logit = alS[s * 4 + hd] + ald;
    logit = logit >= 0.f ? logit : 0.2f * logit;
    float w = __expf(logit);  // shift-free softmax: logits bounded by construction
    accv += w * (float)h1[(size_t)s * HID + f];
    accw += w;
  }
  float v = (cnt > 0) ? accv / accw : 0.f;
  v += b1[f];
  float s = v, ss = v * v;
#pragma unroll
  for (int off = 32; off; off >>= 1) { s += __shfl_xor(s, off); ss += __shfl_xor(ss, off); }
  if ((f & 63) == 0) { red[f >> 6] = s; red[4 + (f >> 6)] = ss; }
  __syncthreads();
  float tot = red[0] + red[1] + red[2] + red[3];
  float tss = red[4] + red[5] + red[6] + red[7];
  float mu = tot * (1.f / HID);
  float var = tss * (1.f / HID) - mu * mu;
  float y = (v - mu) * rsqrtf(var + 1e-5f) * g1[f] + be1[f];
  y = y > 0.f ? y : __expf(y) - 1.f;  // ELU
  hln[(size_t)n * HID + f] = (bf16)y;
}

// ---------------- fused gather-aggregate + LN, layer 2 ----------------
__global__ __launch_bounds__(64) void k_agg_ln2(const int* __restrict__ rowstart,
                                                const int* __restrict__ deg,
                                                const int* __restrict__ csr,
                                                const float* __restrict__ h2,
                                                const float* __restrict__ alS,
                                                const float* __restrict__ alD,
                                                const float* __restrict__ b2,
                                                const float* __restrict__ g2,
                                                const float* __restrict__ be2,
                                                float* __restrict__ out) {
  int n = blockIdx.x, f = threadIdx.x;
  int start = rowstart[n], cnt = deg[n];
  float ald = alD[n];
  float accv = 0.f, accw = 0.f;
  for (int j = 0; j < cnt; j++) {
    int s = csr[start + j];
    float logit = alS[s] + ald;
    logit = logit >= 0.f ? logit : 0.2f * logit;
    float w = __expf(logit);
    accv += w * h2[(size_t)s * OUTD + f];
    accw += w;
  }
  float v = (cnt > 0) ? accv / accw : 0.f;
  v += b2[f];
  float s = v, ss = v * v;
#pragma unroll
  for (int off = 32; off; off >>= 1) { s += __shfl_xor(s, off); ss += __shfl_xor(ss, off); }
  float mu = s * (1.f / OUTD);
  float var = ss * (1.f / OUTD) - mu * mu;
  out[(size_t)n * OUTD + f] = (v - mu) * rsqrtf(var + 1e-5f) * g2[f] + be2[f];
}

extern "C" void kernel_launch(void* const* d_in, const int* in_sizes, int n_in,
                              void* d_out, int out_size, void* d_ws, size_t ws_size,
                              hipStream_t stream) {
  const float* x    = (const float*)d_in[0];
  const int*   ei   = (const int*)d_in[1];
  const int*   et   = (const int*)d_in[2];
  const float* eemb = (const float*)d_in[3];
  const float* W1   = (const float*)d_in[4];
  const float* as1  = (const float*)d_in[5];
  const float* ad1  = (const float*)d_in[6];
  const float* b1   = (const float*)d_in[7];
  const float* g1   = (const float*)d_in[8];
  const float* be1  = (const float*)d_in[9];
  const float* W2   = (const float*)d_in[10];
  const float* as2  = (const float*)d_in[11];
  const float* ad2  = (const float*)d_in[12];
  const float* b2   = (const float*)d_in[13];
  const float* g2   = (const float*)d_in[14];
  const float* be2  = (const float*)d_in[15];
  float* out = (float*)d_out;

  char* base = (char*)d_ws;
  size_t off = 0;
  auto alloc = [&](size_t bytes) -> void* {
    void* p = base + off;
    off = (off + bytes + 255) & ~(size_t)255;
    return p;
  };
  int*   le    = (int*)alloc((size_t)NN * 4);
  int*   deg   = (int*)alloc((size_t)NN * 4);
  int*   excl  = (int*)alloc((size_t)NN * 4);
  int*   bsum  = (int*)alloc(256 * 4);
  int*   bbase = (int*)alloc(256 * 4);
  int*   rowst = (int*)alloc((size_t)NN * 4);
  int*   cur   = (int*)alloc((size_t)NN * 4);
  int*   csr   = (int*)alloc((size_t)NE * 4);
  bf16*  h1    = (bf16*)alloc((size_t)NN * HID * 2);
  float* alS1  = (float*)alloc((size_t)NN * 4 * 4);
  float* alD1  = (float*)alloc((size_t)NN * 4 * 4);
  bf16*  hln   = (bf16*)alloc((size_t)NN * HID * 2);
  float* h2    = (float*)alloc((size_t)NN * OUTD * 4);
  float* alS2  = (float*)alloc((size_t)NN * 4);
  float* alD2  = (float*)alloc((size_t)NN * 4);
  bf16*  W1t   = (bf16*)alloc((size_t)HID * IND * 2);
  bf16*  W2t   = (bf16*)alloc((size_t)OUTD * HID * 2);
  float* eembz = (float*)alloc((size_t)7 * IND * 4);

  hipMemsetAsync(le, 0xFF, (size_t)NN * 4, stream);  // -1
  hipMemsetAsync(deg, 0, (size_t)NN * 4, stream);

  // CSR build + last-edge index + zero-padded edge-emb table
  k_edge_prep<<<(NE + 255) / 256, 256, 0, stream>>>(ei, le, deg);
  k_eembz<<<(7 * IND + 255) / 256, 256, 0, stream>>>(eemb, eembz);
  k_scan_block<<<NB, 256, 0, stream>>>(deg, excl, bsum);
  k_scan_partials<<<1, 256, 0, stream>>>(bsum, bbase);
  k_add_base<<<NB, 256, 0, stream>>>(excl, bbase, rowst, cur);
  k_scatter_csr<<<(NE + 255) / 256, 256, 0, stream>>>(ei, cur, csr);

  // weights
  k_transpose<<<dim3(3, HID), 256, 0, stream>>>(W1, W1t, IND, HID);
  k_transpose<<<dim3(1, OUTD), 256, 0, stream>>>(W2, W2t, HID, OUTD);

  // layer 1: fused (x + edge_emb) -> GEMM -> h1 + logits
  k_gemm_bt<bf16, true><<<dim3(2, (NN + 127) / 128), 256, 0, stream>>>(
      nullptr, x, le, et, eembz, W1t, h1, NN, IND, HID, as1, ad1, alS1, alD1, 4);
  k_agg_ln1<<<NN, 256, 0, stream>>>(rowst, deg, csr, h1, alS1, alD1, b1, g1, be1, hln);

  // layer 2: GEMM -> h2 + logits
  k_gemm_bt<float, false><<<dim3(1, (NN + 127) / 128), 256, 0, stream>>>(
      hln, nullptr, nullptr, nullptr, nullptr, W2t, h2, NN, HID, OUTD, as2, ad2, alS2, alD2, 1);
  k_agg_ln2<<<NN, 64, 0, stream>>>(rowst, deg, csr, h2, alS2, alD2, b2, g2, be2, out);
}